// Round 7
// baseline (1164.506 us; speedup 1.0000x reference)
//
#include <hip/hip_runtime.h>
#include <hip/hip_fp16.h>

// ---------------------------------------------------------------------------
// GATv2 3-layer GNN encoder. N=50000 nodes, E=800000 edges, dims 128.
// CSR build + degree-sort + edge-stream permute (once); per layer:
// [prep_w (W->W^T bf16), MFMA dual GEMM (xlh fp16-interleaved + xr fp32 from
// bf16 X), fused edge-score + segment-softmax + aggregate + bias + LN + ReLU].
// ---------------------------------------------------------------------------

typedef __attribute__((ext_vector_type(8))) short bf16x8;
typedef __attribute__((ext_vector_type(4))) float f32x4;

__device__ inline ushort f2bf(float f) {
  unsigned u = __float_as_uint(f);
  u += 0x7FFF + ((u >> 16) & 1);  // round-to-nearest-even
  return (ushort)(u >> 16);
}

__device__ inline ushort f2h(float f) {
  __half h = __float2half(f);
  return *(ushort*)&h;
}

// ---------------- CSR build ----------------

__global__ __launch_bounds__(256) void hist_kernel(const int* __restrict__ dst,
                                                   int* __restrict__ deg, int nE) {
  int i = blockIdx.x * 256 + threadIdx.x;
  if (i < nE) atomicAdd(&deg[dst[i]], 1);
}

__global__ __launch_bounds__(1024) void scan_kernel(const int* __restrict__ deg,
                                                    int* __restrict__ rowptr, int n) {
  __shared__ int wsum[16];
  __shared__ int wbase[16];
  int tid = threadIdx.x, wid = tid >> 6, lane = tid & 63;
  if (tid == 0) rowptr[0] = 0;
  int carry = 0;
  for (int base = 0; base < n; base += 1024) {
    int i = base + tid;
    int v = (i < n) ? deg[i] : 0;
#pragma unroll
    for (int o = 1; o < 64; o <<= 1) {
      int t = __shfl_up(v, o);
      if (lane >= o) v += t;
    }
    if (lane == 63) wsum[wid] = v;
    __syncthreads();
    if (wid == 0 && lane < 16) {
      int s = wsum[lane];
#pragma unroll
      for (int o = 1; o < 16; o <<= 1) {
        int t = __shfl_up(s, o);
        if (lane >= o) s += t;
      }
      wbase[lane] = s;
    }
    __syncthreads();
    int myb = (wid > 0) ? wbase[wid - 1] : 0;
    int tot = wbase[15];
    if (i < n) rowptr[i + 1] = carry + myb + v;
    carry += tot;
    __syncthreads();
  }
}

__global__ __launch_bounds__(256) void scatter_kernel(const int* __restrict__ dst,
                                                      const int* __restrict__ rowptr,
                                                      int* __restrict__ cnt,
                                                      int* __restrict__ eperm, int nE) {
  int i = blockIdx.x * 256 + threadIdx.x;
  if (i < nE) {
    int d = dst[i];
    int p = atomicAdd(&cnt[d], 1);
    eperm[rowptr[d] + p] = i;
  }
}

__global__ __launch_bounds__(256) void deg_hist(const int* __restrict__ rowptr,
                                                int* __restrict__ dh, int nN) {
  int i = blockIdx.x * 256 + threadIdx.x;
  if (i < nN) {
    int dg = min(rowptr[i + 1] - rowptr[i], 255);
    atomicAdd(&dh[dg], 1);
  }
}

__global__ __launch_bounds__(256) void deg_scan(const int* __restrict__ dh,
                                                int* __restrict__ dbase) {
  __shared__ int s[256];
  int t = threadIdx.x;
  s[t] = dh[t];
  __syncthreads();
  for (int ofs = 1; ofs < 256; ofs <<= 1) {
    int v = (t >= ofs) ? s[t - ofs] : 0;
    __syncthreads();
    s[t] += v;
    __syncthreads();
  }
  dbase[t] = s[255] - s[t];
}

__global__ __launch_bounds__(256) void deg_scatter(const int* __restrict__ rowptr,
                                                   const int* __restrict__ dbase,
                                                   int* __restrict__ dcnt,
                                                   int* __restrict__ nodeorder, int nN) {
  int i = blockIdx.x * 256 + threadIdx.x;
  if (i < nN) {
    int dg = min(rowptr[i + 1] - rowptr[i], 255);
    int p = atomicAdd(&dcnt[dg], 1);
    nodeorder[dbase[dg] + p] = i;
  }
}

// ea_perm[j] = ea[eperm[j]] (fp32, CSR order), src_perm[j] = src[eperm[j]].
__global__ __launch_bounds__(256) void prep_edges(const float* __restrict__ ea,
                                                  const int* __restrict__ eperm,
                                                  const int* __restrict__ src,
                                                  float* __restrict__ ea_perm,
                                                  int* __restrict__ src_perm, int nE) {
  int t = blockIdx.x * 256 + threadIdx.x;
  int j = t >> 3, ch = (t & 7) << 2;
  if (j < nE) {
    int e = eperm[j];
    *(float4*)&ea_perm[(size_t)j * 32 + ch] = *(const float4*)&ea[(size_t)e * 32 + ch];
    if (ch == 0) src_perm[j] = src[e];
  }
}

// ---------------- bf16 prep ----------------

__global__ __launch_bounds__(256) void convert_x(const float* __restrict__ x,
                                                 ushort* __restrict__ xb, int n8) {
  int i = blockIdx.x * 256 + threadIdx.x;
  if (i < n8) {
    float4 a = ((const float4*)x)[i * 2];
    float4 b = ((const float4*)x)[i * 2 + 1];
    union { ushort r[8]; uint4 v; } u;
    u.r[0] = f2bf(a.x); u.r[1] = f2bf(a.y); u.r[2] = f2bf(a.z); u.r[3] = f2bf(a.w);
    u.r[4] = f2bf(b.x); u.r[5] = f2bf(b.y); u.r[6] = f2bf(b.z); u.r[7] = f2bf(b.w);
    ((uint4*)xb)[i] = u.v;
  }
}

// wt[n][k] = bf16(W[k][n]) for both weight matrices.
__global__ __launch_bounds__(256) void prep_w(const float* __restrict__ Wl,
                                              const float* __restrict__ Wr,
                                              ushort* __restrict__ wt1,
                                              ushort* __restrict__ wt2) {
  int idx = blockIdx.x * 256 + threadIdx.x;
  int mat = idx >> 14, rem = idx & 16383;
  int n = rem >> 7, k = rem & 127;
  const float* W = mat ? Wr : Wl;
  ushort* wt = mat ? wt2 : wt1;
  wt[n * 128 + k] = f2bf(W[(size_t)k * 128 + n]);
}

// ---------------- MFMA dual GEMM ----------------
// xlh[row][c] (uint32) = fp16(xl[row][c]) | fp16(xl[row][c+64])<<16, c<64.
// xr fp32 plain. X bf16 [nrows][128], wt = W^T bf16 [128n][128k].
#define XPAD 136

__device__ inline bf16x8 load_frag(const ushort* p) {
  union { bf16x8 v; unsigned long long q[2]; } u;
  u.q[0] = *(const unsigned long long*)p;
  u.q[1] = *(const unsigned long long*)(p + 16);
  return u.v;
}

__global__ __launch_bounds__(512) void gemm_mfma_dual(
    const ushort* __restrict__ xb, const ushort* __restrict__ wt1,
    const ushort* __restrict__ wt2, const float* __restrict__ b1,
    const float* __restrict__ b2, ushort* __restrict__ xlh,
    float* __restrict__ y2, int nrows) {
  __shared__ ushort Xs[128 * XPAD];
  __shared__ ushort W1s[128 * XPAD];
  __shared__ ushort W2s[128 * XPAD];
  const int tid = threadIdx.x;
  const int r0 = blockIdx.x * 128;

#pragma unroll
  for (int i = 0; i < 4; ++i) {
    int c = tid + i * 512;
    int row = c >> 4, kc = (c & 15) << 3;
    int gr = min(r0 + row, nrows - 1);
    *(uint4*)&Xs[row * XPAD + kc] = *(const uint4*)&xb[(size_t)gr * 128 + kc];
    *(uint4*)&W1s[row * XPAD + kc] = *(const uint4*)&wt1[row * 128 + kc];
    *(uint4*)&W2s[row * XPAD + kc] = *(const uint4*)&wt2[row * 128 + kc];
  }
  __syncthreads();

  const int wid = tid >> 6, lane = tid & 63;
  const int lr = lane & 15, lg = lane >> 4;
  const int RB = (wid & 3) * 32, CB = (wid >> 2) * 64;

  f32x4 acc1[2][4] = {{{0.f}}};
  f32x4 acc2[2][4] = {{{0.f}}};

#pragma unroll
  for (int ks = 0; ks < 4; ++ks) {
    const int kb = ks * 32 + lg * 4;
    bf16x8 a0 = load_frag(&Xs[(RB + lr) * XPAD + kb]);
    bf16x8 a1 = load_frag(&Xs[(RB + 16 + lr) * XPAD + kb]);
#pragma unroll
    for (int nt = 0; nt < 4; ++nt) {
      const int n = CB + nt * 16 + lr;
      bf16x8 bf1 = load_frag(&W1s[n * XPAD + kb]);
      acc1[0][nt] = __builtin_amdgcn_mfma_f32_16x16x32_bf16(a0, bf1, acc1[0][nt], 0, 0, 0);
      acc1[1][nt] = __builtin_amdgcn_mfma_f32_16x16x32_bf16(a1, bf1, acc1[1][nt], 0, 0, 0);
      bf16x8 bf2 = load_frag(&W2s[n * XPAD + kb]);
      acc2[0][nt] = __builtin_amdgcn_mfma_f32_16x16x32_bf16(a0, bf2, acc2[0][nt], 0, 0, 0);
      acc2[1][nt] = __builtin_amdgcn_mfma_f32_16x16x32_bf16(a1, bf2, acc2[1][nt], 0, 0, 0);
    }
  }

#pragma unroll
  for (int nt = 0; nt < 4; ++nt) {
    const int col = CB + nt * 16 + lr;
    const float bb1 = b1[col], bb2 = b2[col];
    const int hoff = ((col & 63) << 1) | (col >> 6);  // interleaved fp16 offset
#pragma unroll
    for (int mt = 0; mt < 2; ++mt) {
#pragma unroll
      for (int r = 0; r < 4; ++r) {
        int gr = r0 + RB + mt * 16 + lg * 4 + r;
        if (gr < nrows) {
          xlh[(size_t)gr * 128 + hoff] = f2h(acc1[mt][nt][r] + bb1);
          y2[(size_t)gr * 128 + col] = acc2[mt][nt][r] + bb2;
        }
      }
    }
  }
}

// ---------------- fused GATv2 layer ----------------
// ONE 64-lane wave per node. Thread owns dims cL=lane, cH=lane+64; xl gather
// is ONE dword (fp16 pair) per edge per thread. 4 edges in flight. We columns
// pinned in VGPRs. PERM: ea/src read CSR-ordered (sequential s_loads).
template <int H, bool OB, bool PERM>
__global__ __launch_bounds__(256) void fused_gat(const ushort* __restrict__ xlh,
                                                 const float* __restrict__ xr,
                                                 const float* __restrict__ ea,
                                                 const float* __restrict__ We,
                                                 const float* __restrict__ att,
                                                 const int* __restrict__ rowptr,
                                                 const int* __restrict__ eperm,
                                                 const int* __restrict__ src,
                                                 const int* __restrict__ nodeorder,
                                                 const float* __restrict__ bias,
                                                 const float* __restrict__ gam,
                                                 const float* __restrict__ bet,
                                                 float* __restrict__ out,
                                                 ushort* __restrict__ outb, int nN) {
  const int wid = threadIdx.x >> 6;
  const int lane = threadIdx.x & 63;
  const int bn = blockIdx.x * 4 + wid;
  if (bn >= nN) return;
  const int n = __builtin_amdgcn_readfirstlane(nodeorder[bn]);
  const int rb = __builtin_amdgcn_readfirstlane(rowptr[n]);
  const int re = __builtin_amdgcn_readfirstlane(rowptr[n + 1]);
  const int cL = lane, cH = lane + 64;
  const uint* __restrict__ xlw = (const uint*)xlh;

  float WcL[32], WcH[32];
#pragma unroll
  for (int k = 0; k < 32; ++k) {
    WcL[k] = We[k * 128 + cL];
    WcH[k] = We[k * 128 + cH];
  }
#pragma unroll
  for (int k = 0; k < 32; ++k) {  // pin in VGPRs (stop rematerialized loads)
    asm volatile("" : "+v"(WcL[k]), "+v"(WcH[k]));
  }
  const float attL = att[cL] * 1.44269504088896f;  // fold 1/ln2 -> exp2
  const float attH = att[cH] * 1.44269504088896f;
  const float xrL = xr[(size_t)n * 128 + cL];
  const float xrH = xr[(size_t)n * 128 + cH];

  float dL = 0.f, dH = 0.f, accL = 0.f, accH = 0.f;

  for (int b0 = rb; b0 < re; b0 += 64) {
    const int cnt = min(64, re - b0);
    const int jj = b0 + lane;
    int sv, ev = 0;
    if (PERM) {
      sv = (jj < re) ? src[jj] : 0;  // src_perm: coalesced
    } else {
      ev = (jj < re) ? eperm[jj] : 0;
      sv = (jj < re) ? src[ev] : 0;
    }

    for (int i = 0; i < cnt; i += 4) {
      const int i0 = i, i1 = min(i + 1, cnt - 1), i2 = min(i + 2, cnt - 1),
                i3 = min(i + 3, cnt - 1);
      const int s0 = __builtin_amdgcn_readlane(sv, i0);
      const int s1 = __builtin_amdgcn_readlane(sv, i1);
      const int s2 = __builtin_amdgcn_readlane(sv, i2);
      const int s3 = __builtin_amdgcn_readlane(sv, i3);

      const uint u0 = xlw[(size_t)s0 * 64 + lane];  // 256B coalesced
      const uint u1 = xlw[(size_t)s1 * 64 + lane];
      const uint u2 = xlw[(size_t)s2 * 64 + lane];
      const uint u3 = xlw[(size_t)s3 * 64 + lane];

      size_t r0o, r1o, r2o, r3o;
      if (PERM) {  // sequential rows in CSR order
        r0o = (size_t)(b0 + i0) * 32;
        r1o = (size_t)(b0 + i1) * 32;
        r2o = (size_t)(b0 + i2) * 32;
        r3o = (size_t)(b0 + i3) * 32;
      } else {
        r0o = (size_t)__builtin_amdgcn_readlane(ev, i0) * 32;
        r1o = (size_t)__builtin_amdgcn_readlane(ev, i1) * 32;
        r2o = (size_t)__builtin_amdgcn_readlane(ev, i2) * 32;
        r3o = (size_t)__builtin_amdgcn_readlane(ev, i3) * 32;
      }
      const float* r0p = ea + r0o;
      const float* r1p = ea + r1o;
      const float* r2p = ea + r2o;
      const float* r3p = ea + r3o;

      const float2 f0 = __half22float2(*(const __half2*)&u0);
      const float2 f1 = __half22float2(*(const __half2*)&u1);
      const float2 f2 = __half22float2(*(const __half2*)&u2);
      const float2 f3 = __half22float2(*(const __half2*)&u3);

      float m0L = f0.x + xrL, m0H = f0.y + xrH;
      float m1L = f1.x + xrL, m1H = f1.y + xrH;
      float m2L = f2.x + xrL, m2H = f2.y + xrH;
      float m3L = f3.x + xrL, m3H = f3.y + xrH;
#pragma unroll
      for (int k = 0; k < 32; k += 4) {
        float4 q0 = *(const float4*)(r0p + k);
        float4 q1 = *(const float4*)(r1p + k);
        float4 q2 = *(const float4*)(r2p + k);
        float4 q3 = *(const float4*)(r3p + k);
        m0L += q0.x * WcL[k] + q0.y * WcL[k + 1] + q0.z * WcL[k + 2] + q0.w * WcL[k + 3];
        m0H += q0.x * WcH[k] + q0.y * WcH[k + 1] + q0.z * WcH[k + 2] + q0.w * WcH[k + 3];
        m1L += q1.x * WcL[k] + q1.y * WcL[k + 1] + q1.z * WcL[k + 2] + q1.w * WcL[k + 3];
        m1H += q1.x * WcH[k] + q1.y * WcH[k + 1] + q1.z * WcH[k + 2] + q1.w * WcH[k + 3];
        m2L += q2.x * WcL[k] + q2.y * WcL[k + 1] + q2.z * WcL[k + 2] + q2.w * WcL[k + 3];
        m2H += q2.x * WcH[k] + q2.y * WcH[k + 1] + q2.z * WcH[k + 2] + q2.w * WcH[k + 3];
        m3L += q3.x * WcL[k] + q3.y * WcL[k + 1] + q3.z * WcL[k + 2] + q3.w * WcL[k + 3];
        m3H += q3.x * WcH[k] + q3.y * WcH[k + 1] + q3.z * WcH[k + 2] + q3.w * WcH[k + 3];
      }
      float p0L = fmaxf(m0L, 0.2f * m0L) * attL;
      float p0H = fmaxf(m0H, 0.2f * m0H) * attH;
      float p1L = fmaxf(m1L, 0.2f * m1L) * attL;
      float p1H = fmaxf(m1H, 0.2f * m1H) * attH;
      float p2L = fmaxf(m2L, 0.2f * m2L) * attL;
      float p2H = fmaxf(m2H, 0.2f * m2H) * attH;
      float p3L = fmaxf(m3L, 0.2f * m3L) * attL;
      float p3H = fmaxf(m3H, 0.2f * m3H) * attH;

      if (H == 4) {
#pragma unroll
        for (int o = 16; o >= 1; o >>= 1) {  // 32-lane group == head
          p0L += __shfl_xor(p0L, o); p0H += __shfl_xor(p0H, o);
          p1L += __shfl_xor(p1L, o); p1H += __shfl_xor(p1H, o);
          p2L += __shfl_xor(p2L, o); p2H += __shfl_xor(p2H, o);
          p3L += __shfl_xor(p3L, o); p3H += __shfl_xor(p3H, o);
        }
      } else {
        float p0 = p0L + p0H, p1 = p1L + p1H, p2 = p2L + p2H, p3 = p3L + p3H;
#pragma unroll
        for (int o = 32; o >= 1; o >>= 1) {
          p0 += __shfl_xor(p0, o); p1 += __shfl_xor(p1, o);
          p2 += __shfl_xor(p2, o); p3 += __shfl_xor(p3, o);
        }
        p0L = p0H = p0; p1L = p1H = p1; p2L = p2H = p2; p3L = p3H = p3;
      }

      float w0L = exp2f(fminf(p0L, 115.4f));
      float w0H = exp2f(fminf(p0H, 115.4f));
      float w1L = exp2f(fminf(p1L, 115.4f));
      float w1H = exp2f(fminf(p1H, 115.4f));
      float w2L = exp2f(fminf(p2L, 115.4f));
      float w2H = exp2f(fminf(p2H, 115.4f));
      float w3L = exp2f(fminf(p3L, 115.4f));
      float w3H = exp2f(fminf(p3H, 115.4f));
      if (i + 1 >= cnt) { w1L = 0.f; w1H = 0.f; }
      if (i + 2 >= cnt) { w2L = 0.f; w2H = 0.f; }
      if (i + 3 >= cnt) { w3L = 0.f; w3H = 0.f; }
      dL += (w0L + w1L) + (w2L + w3L);
      dH += (w0H + w1H) + (w2H + w3H);
      accL += (w0L * f0.x + w1L * f1.x) + (w2L * f2.x + w3L * f3.x);
      accH += (w0H * f0.y + w1H * f1.y) + (w2H * f2.y + w3H * f3.y);
    }
  }

  const float rdL = (dL > 0.f) ? 1.f / dL : 0.f;
  const float rdH = (dH > 0.f) ? 1.f / dH : 0.f;
  float y0 = accL * rdL + bias[cL];
  float y1 = accH * rdH + bias[cH];

  float sm = y0 + y1, sq = y0 * y0 + y1 * y1;
#pragma unroll
  for (int o = 32; o >= 1; o >>= 1) {
    sm += __shfl_xor(sm, o);
    sq += __shfl_xor(sq, o);
  }
  const float mu = sm * (1.f / 128.f);
  const float var = sq * (1.f / 128.f) - mu * mu;
  const float rstd = rsqrtf(var + 1e-5f);
  const float o0 = fmaxf((y0 - mu) * rstd * gam[cL] + bet[cL], 0.f);
  const float o1 = fmaxf((y1 - mu) * rstd * gam[cH] + bet[cH], 0.f);
  if (OB) {
    outb[(size_t)n * 128 + cL] = f2bf(o0);
    outb[(size_t)n * 128 + cH] = f2bf(o1);
  } else {
    out[(size_t)n * 128 + cL] = o0;
    out[(size_t)n * 128 + cH] = o1;
  }
}

extern "C" void kernel_launch(void* const* d_in, const int* in_sizes, int n_in,
                              void* d_out, int out_size, void* d_ws, size_t ws_size,
                              hipStream_t stream) {
  const float* x = (const float*)d_in[0];
  const float* ea = (const float*)d_in[1];
  const int* src = (const int*)d_in[2];
  const int* dst = (const int*)d_in[3];
  const int N = in_sizes[0] / 128;
  const int E = in_sizes[2];

  char* w = (char*)d_ws;
  auto alloc = [&](size_t bytes) {
    char* p = w;
    w += (bytes + 255) & ~(size_t)255;
    return p;
  };
  ushort* xlh = (ushort*)alloc((size_t)N * 128 * 2);
  float* xr = (float*)alloc((size_t)N * 128 * 4);
  ushort* xb = (ushort*)alloc((size_t)N * 128 * 2);
  ushort* wt1 = (ushort*)alloc(128 * 128 * 2);
  ushort* wt2 = (ushort*)alloc(128 * 128 * 2);
  int* eperm = (int*)alloc((size_t)E * 4);
  int* rowptr = (int*)alloc((size_t)(N + 1) * 4);
  int* deg = (int*)alloc((size_t)N * 4);
  int* cnt = (int*)alloc((size_t)N * 4);
  int* nodeorder = (int*)alloc((size_t)N * 4);
  int* dh = (int*)alloc(256 * 4);
  int* dbase = (int*)alloc(256 * 4);
  int* dcnt = (int*)alloc(256 * 4);
  // optional (workspace permitting): CSR-ordered edge streams
  size_t used = (size_t)(w - (char*)d_ws);
  size_t perm_need = ((size_t)E * 32 * 4 + 256) + ((size_t)E * 4 + 256);
  const bool PERM_OK = (used + perm_need <= ws_size);
  float* ea_perm = nullptr;
  int* src_perm = nullptr;
  if (PERM_OK) {
    ea_perm = (float*)alloc((size_t)E * 32 * 4);
    src_perm = (int*)alloc((size_t)E * 4);
  }

  // CSR by dst + degree-descending node order (src/dst constant across layers)
  hipMemsetAsync(deg, 0, (size_t)N * 4, stream);
  hipMemsetAsync(cnt, 0, (size_t)N * 4, stream);
  hipMemsetAsync(dh, 0, 256 * 4, stream);
  hipMemsetAsync(dcnt, 0, 256 * 4, stream);
  hist_kernel<<<(E + 255) / 256, 256, 0, stream>>>(dst, deg, E);
  scan_kernel<<<1, 1024, 0, stream>>>(deg, rowptr, N);
  scatter_kernel<<<(E + 255) / 256, 256, 0, stream>>>(dst, rowptr, cnt, eperm, E);
  deg_hist<<<(N + 255) / 256, 256, 0, stream>>>(rowptr, dh, N);
  deg_scan<<<1, 256, 0, stream>>>(dh, dbase);
  deg_scatter<<<(N + 255) / 256, 256, 0, stream>>>(rowptr, dbase, dcnt, nodeorder, N);
  if (PERM_OK) {
    prep_edges<<<(E * 8 + 255) / 256, 256, 0, stream>>>(ea, eperm, src, ea_perm,
                                                        src_perm, E);
  }

  int n8 = N * 128 / 8;
  convert_x<<<(n8 + 255) / 256, 256, 0, stream>>>(x, xb, n8);

  for (int l = 0; l < 3; ++l) {
    int bi = 4 + 9 * l;
    const float* Wl = (const float*)d_in[bi + 0];
    const float* bl = (const float*)d_in[bi + 1];
    const float* Wr = (const float*)d_in[bi + 2];
    const float* br = (const float*)d_in[bi + 3];
    const float* We = (const float*)d_in[bi + 4];
    const float* att = (const float*)d_in[bi + 5];
    const float* bo = (const float*)d_in[bi + 6];
    const float* gg = (const float*)d_in[bi + 7];
    const float* be = (const float*)d_in[bi + 8];

    prep_w<<<128, 256, 0, stream>>>(Wl, Wr, wt1, wt2);
    gemm_mfma_dual<<<(N + 127) / 128, 512, 0, stream>>>(xb, wt1, wt2, bl, br, xlh, xr, N);
    int nGrid = (N + 3) / 4;
    const float* eaK = PERM_OK ? ea_perm : ea;
    const int* srcK = PERM_OK ? src_perm : src;
    if (l < 2) {
      if (PERM_OK)
        fused_gat<4, true, true><<<nGrid, 256, 0, stream>>>(
            xlh, xr, eaK, We, att, rowptr, eperm, srcK, nodeorder, bo, gg, be,
            nullptr, xb, N);
      else
        fused_gat<4, true, false><<<nGrid, 256, 0, stream>>>(
            xlh, xr, eaK, We, att, rowptr, eperm, srcK, nodeorder, bo, gg, be,
            nullptr, xb, N);
    } else {
      if (PERM_OK)
        fused_gat<1, false, true><<<nGrid, 256, 0, stream>>>(
            xlh, xr, eaK, We, att, rowptr, eperm, srcK, nodeorder, bo, gg, be,
            (float*)d_out, nullptr, N);
      else
        fused_gat<1, false, false><<<nGrid, 256, 0, stream>>>(
            xlh, xr, eaK, We, att, rowptr, eperm, srcK, nodeorder, bo, gg, be,
            (float*)d_out, nullptr, N);
    }
  }
}

// Round 9
// 924.756 us; speedup vs baseline: 1.2593x; 1.2593x over previous
//
#include <hip/hip_runtime.h>
#include <hip/hip_fp16.h>

// ---------------------------------------------------------------------------
// GATv2 3-layer GNN encoder. N=50000 nodes, E=800000 edges, dims 128.
// CSR build + degree-sort + fp16 edge-stream permute (once); per layer:
// [prep_w (W->W^T bf16), MFMA dual GEMM (xlh fp16-interleaved + xr fp32),
// fused edge-score (fdot2) + segment-softmax + aggregate + bias + LN + ReLU].
// ---------------------------------------------------------------------------

typedef __attribute__((ext_vector_type(8))) short bf16x8;
typedef __attribute__((ext_vector_type(4))) float f32x4;
typedef __fp16 h2 __attribute__((ext_vector_type(2)));  // matches builtin types

__device__ inline ushort f2bf(float f) {
  unsigned u = __float_as_uint(f);
  u += 0x7FFF + ((u >> 16) & 1);  // round-to-nearest-even
  return (ushort)(u >> 16);
}

__device__ inline ushort f2h(float f) {
  __half h = __float2half(f);
  return *(ushort*)&h;
}

__device__ inline uint pk2(float a, float b) {
#if __has_builtin(__builtin_amdgcn_cvt_pkrtz)
  h2 r = __builtin_amdgcn_cvt_pkrtz(a, b);
  return *(uint*)&r;
#else
  return (uint)f2h(a) | ((uint)f2h(b) << 16);
#endif
}

__device__ inline float fdot2(uint a, uint b, float c) {
#if __has_builtin(__builtin_amdgcn_fdot2)
  return __builtin_amdgcn_fdot2(*(h2*)&a, *(h2*)&b, c, false);
#else
  float2 fa = __half22float2(*(__half2*)&a);
  float2 fb = __half22float2(*(__half2*)&b);
  return c + fa.x * fb.x + fa.y * fb.y;
#endif
}

__device__ inline uint swz_add(uint p, int o) {  // packed-f16 butterfly step
  int q = __shfl_xor(*(int*)&p, o);
  __half2 r = __hadd2(*(__half2*)&p, *(__half2*)&q);
  return *(uint*)&r;
}

// ---------------- CSR build ----------------

__global__ __launch_bounds__(256) void hist_kernel(const int* __restrict__ dst,
                                                   int* __restrict__ deg, int nE) {
  int i = blockIdx.x * 256 + threadIdx.x;
  if (i < nE) atomicAdd(&deg[dst[i]], 1);
}

__global__ __launch_bounds__(1024) void scan_kernel(const int* __restrict__ deg,
                                                    int* __restrict__ rowptr, int n) {
  __shared__ int wsum[16];
  __shared__ int wbase[16];
  int tid = threadIdx.x, wid = tid >> 6, lane = tid & 63;
  if (tid == 0) rowptr[0] = 0;
  int carry = 0;
  for (int base = 0; base < n; base += 1024) {
    int i = base + tid;
    int v = (i < n) ? deg[i] : 0;
#pragma unroll
    for (int o = 1; o < 64; o <<= 1) {
      int t = __shfl_up(v, o);
      if (lane >= o) v += t;
    }
    if (lane == 63) wsum[wid] = v;
    __syncthreads();
    if (wid == 0 && lane < 16) {
      int s = wsum[lane];
#pragma unroll
      for (int o = 1; o < 16; o <<= 1) {
        int t = __shfl_up(s, o);
        if (lane >= o) s += t;
      }
      wbase[lane] = s;
    }
    __syncthreads();
    int myb = (wid > 0) ? wbase[wid - 1] : 0;
    int tot = wbase[15];
    if (i < n) rowptr[i + 1] = carry + myb + v;
    carry += tot;
    __syncthreads();
  }
}

__global__ __launch_bounds__(256) void scatter_kernel(const int* __restrict__ dst,
                                                      const int* __restrict__ rowptr,
                                                      int* __restrict__ cnt,
                                                      int* __restrict__ eperm, int nE) {
  int i = blockIdx.x * 256 + threadIdx.x;
  if (i < nE) {
    int d = dst[i];
    int p = atomicAdd(&cnt[d], 1);
    eperm[rowptr[d] + p] = i;
  }
}

__global__ __launch_bounds__(256) void deg_hist(const int* __restrict__ rowptr,
                                                int* __restrict__ dh, int nN) {
  int i = blockIdx.x * 256 + threadIdx.x;
  if (i < nN) {
    int dg = min(rowptr[i + 1] - rowptr[i], 255);
    atomicAdd(&dh[dg], 1);
  }
}

__global__ __launch_bounds__(256) void deg_scan(const int* __restrict__ dh,
                                                int* __restrict__ dbase) {
  __shared__ int s[256];
  int t = threadIdx.x;
  s[t] = dh[t];
  __syncthreads();
  for (int ofs = 1; ofs < 256; ofs <<= 1) {
    int v = (t >= ofs) ? s[t - ofs] : 0;
    __syncthreads();
    s[t] += v;
    __syncthreads();
  }
  dbase[t] = s[255] - s[t];
}

__global__ __launch_bounds__(256) void deg_scatter(const int* __restrict__ rowptr,
                                                   const int* __restrict__ dbase,
                                                   int* __restrict__ dcnt,
                                                   int* __restrict__ nodeorder, int nN) {
  int i = blockIdx.x * 256 + threadIdx.x;
  if (i < nN) {
    int dg = min(rowptr[i + 1] - rowptr[i], 255);
    int p = atomicAdd(&dcnt[dg], 1);
    nodeorder[dbase[dg] + p] = i;
  }
}

// ea16[j] = fp16(ea[PERM ? eperm[j] : j]) packed; src_perm[j] = src[eperm[j]].
template <bool PERM>
__global__ __launch_bounds__(256) void prep_edges_h(const float* __restrict__ ea,
                                                    const int* __restrict__ eperm,
                                                    const int* __restrict__ src,
                                                    ushort* __restrict__ ea16,
                                                    int* __restrict__ src_perm, int nE) {
  int t = blockIdx.x * 256 + threadIdx.x;
  int j = t >> 3, ch = (t & 7) << 2;
  if (j < nE) {
    int e = PERM ? eperm[j] : j;
    float4 v = *(const float4*)&ea[(size_t)e * 32 + ch];
    ushort4 h;
    h.x = f2h(v.x); h.y = f2h(v.y); h.z = f2h(v.z); h.w = f2h(v.w);
    *(ushort4*)&ea16[(size_t)j * 32 + ch] = h;
    if (PERM && ch == 0) src_perm[j] = src[e];
  }
}

// ---------------- bf16 prep ----------------

__global__ __launch_bounds__(256) void convert_x(const float* __restrict__ x,
                                                 ushort* __restrict__ xb, int n8) {
  int i = blockIdx.x * 256 + threadIdx.x;
  if (i < n8) {
    float4 a = ((const float4*)x)[i * 2];
    float4 b = ((const float4*)x)[i * 2 + 1];
    union { ushort r[8]; uint4 v; } u;
    u.r[0] = f2bf(a.x); u.r[1] = f2bf(a.y); u.r[2] = f2bf(a.z); u.r[3] = f2bf(a.w);
    u.r[4] = f2bf(b.x); u.r[5] = f2bf(b.y); u.r[6] = f2bf(b.z); u.r[7] = f2bf(b.w);
    ((uint4*)xb)[i] = u.v;
  }
}

// wt[n][k] = bf16(W[k][n]) for both weight matrices.
__global__ __launch_bounds__(256) void prep_w(const float* __restrict__ Wl,
                                              const float* __restrict__ Wr,
                                              ushort* __restrict__ wt1,
                                              ushort* __restrict__ wt2) {
  int idx = blockIdx.x * 256 + threadIdx.x;
  int mat = idx >> 14, rem = idx & 16383;
  int n = rem >> 7, k = rem & 127;
  const float* W = mat ? Wr : Wl;
  ushort* wt = mat ? wt2 : wt1;
  wt[n * 128 + k] = f2bf(W[(size_t)k * 128 + n]);
}

// ---------------- MFMA dual GEMM ----------------
// 70KB LDS (X + single W buffer staged twice) -> 2 blocks/CU.
#define XPAD 136

__device__ inline bf16x8 load_frag(const ushort* p) {
  union { bf16x8 v; unsigned long long q[2]; } u;
  u.q[0] = *(const unsigned long long*)p;
  u.q[1] = *(const unsigned long long*)(p + 16);
  return u.v;
}

__global__ __launch_bounds__(512) void gemm_mfma_dual(
    const ushort* __restrict__ xb, const ushort* __restrict__ wt1,
    const ushort* __restrict__ wt2, const float* __restrict__ b1,
    const float* __restrict__ b2, ushort* __restrict__ xlh,
    float* __restrict__ y2, int nrows) {
  __shared__ ushort Xs[128 * XPAD];
  __shared__ ushort Ws[128 * XPAD];
  const int tid = threadIdx.x;
  const int r0 = blockIdx.x * 128;

#pragma unroll
  for (int i = 0; i < 4; ++i) {
    int c = tid + i * 512;
    int row = c >> 4, kc = (c & 15) << 3;
    int gr = min(r0 + row, nrows - 1);
    *(uint4*)&Xs[row * XPAD + kc] = *(const uint4*)&xb[(size_t)gr * 128 + kc];
    *(uint4*)&Ws[row * XPAD + kc] = *(const uint4*)&wt1[row * 128 + kc];
  }
  __syncthreads();

  const int wid = tid >> 6, lane = tid & 63;
  const int lr = lane & 15, lg = lane >> 4;
  const int RB = (wid & 3) * 32, CB = (wid >> 2) * 64;

  f32x4 acc1[2][4] = {{{0.f}}};
  f32x4 acc2[2][4] = {{{0.f}}};

#pragma unroll
  for (int ks = 0; ks < 4; ++ks) {
    const int kb = ks * 32 + lg * 4;
    bf16x8 a0 = load_frag(&Xs[(RB + lr) * XPAD + kb]);
    bf16x8 a1 = load_frag(&Xs[(RB + 16 + lr) * XPAD + kb]);
#pragma unroll
    for (int nt = 0; nt < 4; ++nt) {
      const int n = CB + nt * 16 + lr;
      bf16x8 bw = load_frag(&Ws[n * XPAD + kb]);
      acc1[0][nt] = __builtin_amdgcn_mfma_f32_16x16x32_bf16(a0, bw, acc1[0][nt], 0, 0, 0);
      acc1[1][nt] = __builtin_amdgcn_mfma_f32_16x16x32_bf16(a1, bw, acc1[1][nt], 0, 0, 0);
    }
  }
  __syncthreads();
#pragma unroll
  for (int i = 0; i < 4; ++i) {  // stage W2 over W1
    int c = tid + i * 512;
    int row = c >> 4, kc = (c & 15) << 3;
    *(uint4*)&Ws[row * XPAD + kc] = *(const uint4*)&wt2[row * 128 + kc];
  }
  __syncthreads();
#pragma unroll
  for (int ks = 0; ks < 4; ++ks) {
    const int kb = ks * 32 + lg * 4;
    bf16x8 a0 = load_frag(&Xs[(RB + lr) * XPAD + kb]);
    bf16x8 a1 = load_frag(&Xs[(RB + 16 + lr) * XPAD + kb]);
#pragma unroll
    for (int nt = 0; nt < 4; ++nt) {
      const int n = CB + nt * 16 + lr;
      bf16x8 bw = load_frag(&Ws[n * XPAD + kb]);
      acc2[0][nt] = __builtin_amdgcn_mfma_f32_16x16x32_bf16(a0, bw, acc2[0][nt], 0, 0, 0);
      acc2[1][nt] = __builtin_amdgcn_mfma_f32_16x16x32_bf16(a1, bw, acc2[1][nt], 0, 0, 0);
    }
  }

#pragma unroll
  for (int nt = 0; nt < 4; ++nt) {
    const int col = CB + nt * 16 + lr;
    const float bb1 = b1[col], bb2 = b2[col];
    const int hoff = ((col & 63) << 1) | (col >> 6);  // interleaved fp16 offset
#pragma unroll
    for (int mt = 0; mt < 2; ++mt) {
#pragma unroll
      for (int r = 0; r < 4; ++r) {
        int gr = r0 + RB + mt * 16 + lg * 4 + r;
        if (gr < nrows) {
          xlh[(size_t)gr * 128 + hoff] = f2h(acc1[mt][nt][r] + bb1);
          y2[(size_t)gr * 128 + col] = acc2[mt][nt][r] + bb2;
        }
      }
    }
  }
}

// ---------------- fused GATv2 layer ----------------
// ONE 64-lane wave per node. Thread owns dims cL=lane, cH=lane+64.
// ea fp16-packed (fdot2, fp32 accum), Wc packed in 32 VGPRs. 8 edges in
// flight; score reduce = pair-packed f16 butterfly. No LDS, no barriers.
template <int H, bool OB, bool PERM>
__global__ __launch_bounds__(256) void fused_gat(const ushort* __restrict__ xlh,
                                                 const float* __restrict__ xr,
                                                 const ushort* __restrict__ ea16,
                                                 const float* __restrict__ We,
                                                 const float* __restrict__ att,
                                                 const int* __restrict__ rowptr,
                                                 const int* __restrict__ eperm,
                                                 const int* __restrict__ src,
                                                 const int* __restrict__ nodeorder,
                                                 const float* __restrict__ bias,
                                                 const float* __restrict__ gam,
                                                 const float* __restrict__ bet,
                                                 float* __restrict__ out,
                                                 ushort* __restrict__ outb, int nN) {
  const int wid = threadIdx.x >> 6;
  const int lane = threadIdx.x & 63;
  const int bn = blockIdx.x * 4 + wid;
  if (bn >= nN) return;
  const int n = __builtin_amdgcn_readfirstlane(nodeorder[bn]);
  const int rb = __builtin_amdgcn_readfirstlane(rowptr[n]);
  const int re = __builtin_amdgcn_readfirstlane(rowptr[n + 1]);
  const int cL = lane, cH = lane + 64;
  const uint* __restrict__ xlw = (const uint*)xlh;
  const uint* __restrict__ eaw = (const uint*)ea16;

  uint WcLp[16], WcHp[16];
#pragma unroll
  for (int k = 0; k < 16; ++k) {
    WcLp[k] = pk2(We[(2 * k) * 128 + cL], We[(2 * k + 1) * 128 + cL]);
    WcHp[k] = pk2(We[(2 * k) * 128 + cH], We[(2 * k + 1) * 128 + cH]);
  }
#pragma unroll
  for (int k = 0; k < 16; ++k) {
    asm volatile("" : "+v"(WcLp[k]), "+v"(WcHp[k]));  // pin packed Wc
  }
  const float attL = att[cL] * 1.44269504088896f;  // fold 1/ln2 -> exp2
  const float attH = att[cH] * 1.44269504088896f;
  const float xrL = xr[(size_t)n * 128 + cL];
  const float xrH = xr[(size_t)n * 128 + cH];

  float dL = 0.f, dH = 0.f, accL = 0.f, accH = 0.f;

  for (int b0 = rb; b0 < re; b0 += 64) {
    const int cnt = min(64, re - b0);
    const int jj = b0 + lane;
    int sv, ev = 0;
    if (PERM) {
      sv = (jj < re) ? src[jj] : 0;  // src_perm: coalesced
    } else {
      ev = (jj < re) ? eperm[jj] : 0;
      sv = (jj < re) ? src[ev] : 0;
    }

    for (int i = 0; i < cnt; i += 8) {
      uint uu[8];
      float fx[8], fy[8], pl[8], ph[8];
#pragma unroll
      for (int j = 0; j < 8; ++j) {  // issue all gathers first
        int ij = min(i + j, cnt - 1);
        int sj = __builtin_amdgcn_readlane(sv, ij);
        uu[j] = xlw[(size_t)sj * 64 + lane];  // 256B coalesced
      }
#pragma unroll
      for (int j = 0; j < 8; ++j) {
        int ij = min(i + j, cnt - 1);
        size_t ro;
        if (PERM) {
          ro = (size_t)(b0 + ij) * 16;  // sequential fp16 rows (16 dwords)
        } else {
          ro = (size_t)__builtin_amdgcn_readlane(ev, ij) * 16;
        }
        const uint4* ep = (const uint4*)(eaw + ro);  // uniform -> s_load_dwordx4
        uint4 q0 = ep[0], q1 = ep[1], q2 = ep[2], q3 = ep[3];
        float2 f = __half22float2(*(__half2*)&uu[j]);
        float mL = f.x + xrL, mH = f.y + xrH;
        mL = fdot2(q0.x, WcLp[0], mL);  mH = fdot2(q0.x, WcHp[0], mH);
        mL = fdot2(q0.y, WcLp[1], mL);  mH = fdot2(q0.y, WcHp[1], mH);
        mL = fdot2(q0.z, WcLp[2], mL);  mH = fdot2(q0.z, WcHp[2], mH);
        mL = fdot2(q0.w, WcLp[3], mL);  mH = fdot2(q0.w, WcHp[3], mH);
        mL = fdot2(q1.x, WcLp[4], mL);  mH = fdot2(q1.x, WcHp[4], mH);
        mL = fdot2(q1.y, WcLp[5], mL);  mH = fdot2(q1.y, WcHp[5], mH);
        mL = fdot2(q1.z, WcLp[6], mL);  mH = fdot2(q1.z, WcHp[6], mH);
        mL = fdot2(q1.w, WcLp[7], mL);  mH = fdot2(q1.w, WcHp[7], mH);
        mL = fdot2(q2.x, WcLp[8], mL);  mH = fdot2(q2.x, WcHp[8], mH);
        mL = fdot2(q2.y, WcLp[9], mL);  mH = fdot2(q2.y, WcHp[9], mH);
        mL = fdot2(q2.z, WcLp[10], mL); mH = fdot2(q2.z, WcHp[10], mH);
        mL = fdot2(q2.w, WcLp[11], mL); mH = fdot2(q2.w, WcHp[11], mH);
        mL = fdot2(q3.x, WcLp[12], mL); mH = fdot2(q3.x, WcHp[12], mH);
        mL = fdot2(q3.y, WcLp[13], mL); mH = fdot2(q3.y, WcHp[13], mH);
        mL = fdot2(q3.z, WcLp[14], mL); mH = fdot2(q3.z, WcHp[14], mH);
        mL = fdot2(q3.w, WcLp[15], mL); mH = fdot2(q3.w, WcHp[15], mH);
        fx[j] = f.x;
        fy[j] = f.y;
        pl[j] = fmaxf(mL, 0.2f * mL) * attL;
        ph[j] = fmaxf(mH, 0.2f * mH) * attH;
      }
#pragma unroll
      for (int pr = 0; pr < 4; ++pr) {
        const int a = 2 * pr, b = 2 * pr + 1;
        uint packL, packH;
        if (H == 4) {
          packL = pk2(pl[a], pl[b]);
          packH = pk2(ph[a], ph[b]);
#pragma unroll
          for (int o = 16; o >= 1; o >>= 1) {  // 32-lane group == head
            packL = swz_add(packL, o);
            packH = swz_add(packH, o);
          }
        } else {
          packL = pk2(pl[a] + ph[a], pl[b] + ph[b]);
#pragma unroll
          for (int o = 32; o >= 1; o >>= 1) {
            packL = swz_add(packL, o);
          }
          packH = packL;
        }
        float2 sL = __half22float2(*(__half2*)&packL);
        float2 sH = __half22float2(*(__half2*)&packH);
        float wLa = exp2f(fminf(sL.x, 115.f));
        float wLb = exp2f(fminf(sL.y, 115.f));
        float wHa = exp2f(fminf(sH.x, 115.f));
        float wHb = exp2f(fminf(sH.y, 115.f));
        if (i + a >= cnt) { wLa = 0.f; wHa = 0.f; }  // uniform masks
        if (i + b >= cnt) { wLb = 0.f; wHb = 0.f; }
        dL += wLa + wLb;
        dH += wHa + wHb;
        accL += wLa * fx[a] + wLb * fx[b];
        accH += wHa * fy[a] + wHb * fy[b];
      }
    }
  }

  const float rdL = (dL > 0.f) ? 1.f / dL : 0.f;
  const float rdH = (dH > 0.f) ? 1.f / dH : 0.f;
  float y0 = accL * rdL + bias[cL];
  float y1 = accH * rdH + bias[cH];

  float sm = y0 + y1, sq = y0 * y0 + y1 * y1;
#pragma unroll
  for (int o = 32; o >= 1; o >>= 1) {
    sm += __shfl_xor(sm, o);
    sq += __shfl_xor(sq, o);
  }
  const float mu = sm * (1.f / 128.f);
  const float var = sq * (1.f / 128.f) - mu * mu;
  const float rstd = rsqrtf(var + 1e-5f);
  const float o0 = fmaxf((y0 - mu) * rstd * gam[cL] + bet[cL], 0.f);
  const float o1 = fmaxf((y1 - mu) * rstd * gam[cH] + bet[cH], 0.f);
  if (OB) {
    outb[(size_t)n * 128 + cL] = f2bf(o0);
    outb[(size_t)n * 128 + cH] = f2bf(o1);
  } else {
    out[(size_t)n * 128 + cL] = o0;
    out[(size_t)n * 128 + cH] = o1;
  }
}

extern "C" void kernel_launch(void* const* d_in, const int* in_sizes, int n_in,
                              void* d_out, int out_size, void* d_ws, size_t ws_size,
                              hipStream_t stream) {
  const float* x = (const float*)d_in[0];
  const float* ea = (const float*)d_in[1];
  const int* src = (const int*)d_in[2];
  const int* dst = (const int*)d_in[3];
  const int N = in_sizes[0] / 128;
  const int E = in_sizes[2];

  char* w = (char*)d_ws;
  auto alloc = [&](size_t bytes) {
    char* p = w;
    w += (bytes + 255) & ~(size_t)255;
    return p;
  };
  ushort* xlh = (ushort*)alloc((size_t)N * 128 * 2);
  float* xr = (float*)alloc((size_t)N * 128 * 4);
  ushort* xb = (ushort*)alloc((size_t)N * 128 * 2);
  ushort* wt1 = (ushort*)alloc(128 * 128 * 2);
  ushort* wt2 = (ushort*)alloc(128 * 128 * 2);
  int* eperm = (int*)alloc((size_t)E * 4);
  int* rowptr = (int*)alloc((size_t)(N + 1) * 4);
  int* deg = (int*)alloc((size_t)N * 4);
  int* cnt = (int*)alloc((size_t)N * 4);
  int* nodeorder = (int*)alloc((size_t)N * 4);
  int* dh = (int*)alloc(256 * 4);
  int* dbase = (int*)alloc(256 * 4);
  int* dcnt = (int*)alloc(256 * 4);
  ushort* ea16 = (ushort*)alloc((size_t)E * 32 * 2);  // fp16 edge stream
  // optional: CSR-permuted streams (needs only src_perm extra)
  size_t used = (size_t)(w - (char*)d_ws);
  const bool PERM_OK = (used + (size_t)E * 4 + 256 <= ws_size);
  int* src_perm = nullptr;
  if (PERM_OK) src_perm = (int*)alloc((size_t)E * 4);

  // CSR by dst + degree-descending node order (src/dst constant across layers)
  hipMemsetAsync(deg, 0, (size_t)N * 4, stream);
  hipMemsetAsync(cnt, 0, (size_t)N * 4, stream);
  hipMemsetAsync(dh, 0, 256 * 4, stream);
  hipMemsetAsync(dcnt, 0, 256 * 4, stream);
  hist_kernel<<<(E + 255) / 256, 256, 0, stream>>>(dst, deg, E);
  scan_kernel<<<1, 1024, 0, stream>>>(deg, rowptr, N);
  scatter_kernel<<<(E + 255) / 256, 256, 0, stream>>>(dst, rowptr, cnt, eperm, E);
  deg_hist<<<(N + 255) / 256, 256, 0, stream>>>(rowptr, dh, N);
  deg_scan<<<1, 256, 0, stream>>>(dh, dbase);
  deg_scatter<<<(N + 255) / 256, 256, 0, stream>>>(rowptr, dbase, dcnt, nodeorder, N);
  if (PERM_OK)
    prep_edges_h<true><<<((size_t)E * 8 + 255) / 256, 256, 0, stream>>>(
        ea, eperm, src, ea16, src_perm, E);
  else
    prep_edges_h<false><<<((size_t)E * 8 + 255) / 256, 256, 0, stream>>>(
        ea, eperm, src, ea16, nullptr, E);

  int n8 = N * 128 / 8;
  convert_x<<<(n8 + 255) / 256, 256, 0, stream>>>(x, xb, n8);

  for (int l = 0; l < 3; ++l) {
    int bi = 4 + 9 * l;
    const float* Wl = (const float*)d_in[bi + 0];
    const float* bl = (const float*)d_in[bi + 1];
    const float* Wr = (const float*)d_in[bi + 2];
    const float* br = (const float*)d_in[bi + 3];
    const float* We = (const float*)d_in[bi + 4];
    const float* att = (const float*)d_in[bi + 5];
    const float* bo = (const float*)d_in[bi + 6];
    const float* gg = (const float*)d_in[bi + 7];
    const float* be = (const float*)d_in[bi + 8];

    prep_w<<<128, 256, 0, stream>>>(Wl, Wr, wt1, wt2);
    gemm_mfma_dual<<<(N + 127) / 128, 512, 0, stream>>>(xb, wt1, wt2, bl, br, xlh, xr, N);
    int nGrid = (N + 3) / 4;
    const int* srcK = PERM_OK ? src_perm : src;
    if (l < 2) {
      if (PERM_OK)
        fused_gat<4, true, true><<<nGrid, 256, 0, stream>>>(
            xlh, xr, ea16, We, att, rowptr, eperm, srcK, nodeorder, bo, gg, be,
            nullptr, xb, N);
      else
        fused_gat<4, true, false><<<nGrid, 256, 0, stream>>>(
            xlh, xr, ea16, We, att, rowptr, eperm, srcK, nodeorder, bo, gg, be,
            nullptr, xb, N);
    } else {
      if (PERM_OK)
        fused_gat<1, false, true><<<nGrid, 256, 0, stream>>>(
            xlh, xr, ea16, We, att, rowptr, eperm, srcK, nodeorder, bo, gg, be,
            (float*)d_out, nullptr, N);
      else
        fused_gat<1, false, false><<<nGrid, 256, 0, stream>>>(
            xlh, xr, ea16, We, att, rowptr, eperm, srcK, nodeorder, bo, gg, be,
            (float*)d_out, nullptr, N);
    }
  }
}